// Round 1
// baseline (858.637 us; speedup 1.0000x reference)
//
#include <hip/hip_runtime.h>

// Equivariant linear layer, fp32.
//   y0e[n,o]   = sum_i x0e[n,i]  * w0e[o,i]   + bias[o]      (128 out, K=128)
//   y1o[n,o,m] = sum_i x1o[n,i,m]* w1o[o,i,m]                (64 out, K=64, m=0..2)
//   y2e[n,o,m] = sum_i x2e[n,i,m]* w2e[o,i,m]                (32 out, K=32, m=0..4)
// out row per node (480 floats): [0e: 0..127][1o: 128..319][2e: 320..479]
//
// Orientation: lane = output channel (weights per-lane from LDS, transposed
// +1-padded), x is wave-uniform (scalar loads), stores coalesced across lanes.

#define OUT_STRIDE 480

// ---------------- 0e: MUL=128, DIM=1, K=128 ----------------
__global__ __launch_bounds__(256) void lin0e_kernel(
    const float* __restrict__ x, const float* __restrict__ w,
    const float* __restrict__ bias, float* __restrict__ out, int n_nodes) {
  __shared__ float wT[128 * 129];  // wT[k*129 + o] = w[o*128 + k]
  for (int f = threadIdx.x; f < 128 * 128; f += 256) {
    int o = f >> 7, k = f & 127;
    wT[k * 129 + o] = w[f];
  }
  __syncthreads();

  const int o = threadIdx.x & 127;        // output channel
  const int half = threadIdx.x >> 7;      // two node-streams per block
  const int n0 = (blockIdx.x * 2 + half) * 16;
  if (n0 >= n_nodes) return;
  const float bv = bias[o];
  const float* __restrict__ xb = x + (size_t)n0 * 128;
  float* __restrict__ ob = out + (size_t)n0 * OUT_STRIDE + o;

  if (n0 + 16 <= n_nodes) {
    float acc[16];
#pragma unroll
    for (int t = 0; t < 16; ++t) acc[t] = 0.f;
#pragma unroll 4
    for (int k = 0; k < 128; ++k) {
      float wv = wT[k * 129 + o];
#pragma unroll
      for (int t = 0; t < 16; ++t)
        acc[t] = fmaf(xb[t * 128 + k], wv, acc[t]);
    }
#pragma unroll
    for (int t = 0; t < 16; ++t) ob[(size_t)t * OUT_STRIDE] = acc[t] + bv;
  } else {
    for (int t = 0; t < n_nodes - n0; ++t) {
      float acc = 0.f;
      for (int k = 0; k < 128; ++k)
        acc = fmaf(xb[t * 128 + k], wT[k * 129 + o], acc);
      ob[(size_t)t * OUT_STRIDE] = acc + bv;
    }
  }
}

// ---------------- 1o: MUL=64, DIM=3, K=64 ----------------
__global__ __launch_bounds__(256) void lin1o_kernel(
    const float* __restrict__ x, const float* __restrict__ w,
    float* __restrict__ out, int n_nodes) {
  __shared__ float wT[192 * 65];  // wT[(i*3+m)*65 + o] = w[o*192 + i*3 + m]
  for (int f = threadIdx.x; f < 64 * 192; f += 256) {
    int o = f / 192, j = f - o * 192;
    wT[j * 65 + o] = w[f];
  }
  __syncthreads();

  const int o = threadIdx.x & 63;
  const int wv_ = threadIdx.x >> 6;  // wave id = node-stream
  const int n0 = (blockIdx.x * 4 + wv_) * 8;
  if (n0 >= n_nodes) return;
  const float* __restrict__ xb = x + (size_t)n0 * 192;
  float* __restrict__ ob = out + (size_t)n0 * OUT_STRIDE + 128 + o * 3;

  if (n0 + 8 <= n_nodes) {
    float a0[8], a1[8], a2[8];
#pragma unroll
    for (int t = 0; t < 8; ++t) { a0[t] = 0.f; a1[t] = 0.f; a2[t] = 0.f; }
#pragma unroll 2
    for (int k = 0; k < 64; ++k) {
      float w0 = wT[(k * 3 + 0) * 65 + o];
      float w1 = wT[(k * 3 + 1) * 65 + o];
      float w2 = wT[(k * 3 + 2) * 65 + o];
#pragma unroll
      for (int t = 0; t < 8; ++t) {
        a0[t] = fmaf(xb[t * 192 + k * 3 + 0], w0, a0[t]);
        a1[t] = fmaf(xb[t * 192 + k * 3 + 1], w1, a1[t]);
        a2[t] = fmaf(xb[t * 192 + k * 3 + 2], w2, a2[t]);
      }
    }
#pragma unroll
    for (int t = 0; t < 8; ++t) {
      ob[(size_t)t * OUT_STRIDE + 0] = a0[t];
      ob[(size_t)t * OUT_STRIDE + 1] = a1[t];
      ob[(size_t)t * OUT_STRIDE + 2] = a2[t];
    }
  } else {
    for (int t = 0; t < n_nodes - n0; ++t) {
      float a0 = 0.f, a1 = 0.f, a2 = 0.f;
      for (int k = 0; k < 64; ++k) {
        a0 = fmaf(xb[t * 192 + k * 3 + 0], wT[(k * 3 + 0) * 65 + o], a0);
        a1 = fmaf(xb[t * 192 + k * 3 + 1], wT[(k * 3 + 1) * 65 + o], a1);
        a2 = fmaf(xb[t * 192 + k * 3 + 2], wT[(k * 3 + 2) * 65 + o], a2);
      }
      ob[(size_t)t * OUT_STRIDE + 0] = a0;
      ob[(size_t)t * OUT_STRIDE + 1] = a1;
      ob[(size_t)t * OUT_STRIDE + 2] = a2;
    }
  }
}

// ---------------- 2e: MUL=32, DIM=5, K=32 ----------------
// Only 32 output channels: lanes 32..63 duplicate-compute, masked on store.
__global__ __launch_bounds__(256) void lin2e_kernel(
    const float* __restrict__ x, const float* __restrict__ w,
    float* __restrict__ out, int n_nodes) {
  __shared__ float wT[160 * 33];  // wT[(i*5+m)*33 + o] = w[o*160 + i*5 + m]
  for (int f = threadIdx.x; f < 32 * 160; f += 256) {
    int o = f / 160, j = f - o * 160;
    wT[j * 33 + o] = w[f];
  }
  __syncthreads();

  const int o = threadIdx.x & 31;
  const bool store_lane = ((threadIdx.x >> 5) & 1) == 0;
  const int wv_ = threadIdx.x >> 6;
  const int n0 = (blockIdx.x * 4 + wv_) * 8;
  if (n0 >= n_nodes) return;
  const float* __restrict__ xb = x + (size_t)n0 * 160;
  float* __restrict__ ob = out + (size_t)n0 * OUT_STRIDE + 320 + o * 5;

  if (n0 + 8 <= n_nodes) {
    float a[5][8];
#pragma unroll
    for (int m = 0; m < 5; ++m)
#pragma unroll
      for (int t = 0; t < 8; ++t) a[m][t] = 0.f;
    for (int k = 0; k < 32; ++k) {
      float wm[5];
#pragma unroll
      for (int m = 0; m < 5; ++m) wm[m] = wT[(k * 5 + m) * 33 + o];
#pragma unroll
      for (int t = 0; t < 8; ++t) {
#pragma unroll
        for (int m = 0; m < 5; ++m)
          a[m][t] = fmaf(xb[t * 160 + k * 5 + m], wm[m], a[m][t]);
      }
    }
    if (store_lane) {
#pragma unroll
      for (int t = 0; t < 8; ++t) {
#pragma unroll
        for (int m = 0; m < 5; ++m)
          ob[(size_t)t * OUT_STRIDE + m] = a[m][t];
      }
    }
  } else {
    if (store_lane) {
      for (int t = 0; t < n_nodes - n0; ++t) {
        for (int m = 0; m < 5; ++m) {
          float acc = 0.f;
          for (int k = 0; k < 32; ++k)
            acc = fmaf(xb[t * 160 + k * 5 + m], wT[(k * 5 + m) * 33 + o], acc);
          ob[(size_t)t * OUT_STRIDE + m] = acc;
        }
      }
    }
  }
}

extern "C" void kernel_launch(void* const* d_in, const int* in_sizes, int n_in,
                              void* d_out, int out_size, void* d_ws, size_t ws_size,
                              hipStream_t stream) {
  const float* x0e = (const float*)d_in[0];
  const float* x1o = (const float*)d_in[1];
  const float* x2e = (const float*)d_in[2];
  const float* w0e = (const float*)d_in[3];
  const float* w1o = (const float*)d_in[4];
  const float* w2e = (const float*)d_in[5];
  const float* bias = (const float*)d_in[6];
  float* out = (float*)d_out;

  const int n = in_sizes[0] / 128;  // N nodes

  // 0e: 2 streams/block x 16 nodes = 32 nodes/block
  const int b0 = (n + 31) / 32;
  // 1o/2e: 4 streams/block x 8 nodes = 32 nodes/block
  const int b12 = (n + 31) / 32;

  lin0e_kernel<<<b0, 256, 0, stream>>>(x0e, w0e, bias, out, n);
  lin1o_kernel<<<b12, 256, 0, stream>>>(x1o, w1o, out, n);
  lin2e_kernel<<<b12, 256, 0, stream>>>(x2e, w2e, out, n);
}